// Round 15
// baseline (120.129 us; speedup 1.0000x reference)
//
#include <hip/hip_runtime.h>
#include <hip/hip_bf16.h>
#include <stdint.h>

#define H_NUM 16
#define DH 64
#define TSEQ 2048
#define CDIM 1024

typedef short shortx8 __attribute__((ext_vector_type(8)));
typedef short shortx4 __attribute__((ext_vector_type(4)));
typedef float f32x4 __attribute__((ext_vector_type(4)));
typedef unsigned short u16;
typedef unsigned int u32;
typedef unsigned long long u64;

#define MFMA16(a,b,c) __builtin_amdgcn_mfma_f32_16x16x32_bf16(a,b,c,0,0,0)

static __device__ __forceinline__ u16 f2bf(float f) {
  union { float f; u32 u; } v; v.f = f;
  u32 r = v.u + 0x7fffu + ((v.u >> 16) & 1u);
  return (u16)(r >> 16);
}
static __device__ __forceinline__ float bf2f(u16 b) {
  union { u32 u; float f; } v; v.u = ((u32)b) << 16;
  return v.f;
}

static __device__ __forceinline__ void gload_lds16(const void* g, void* l) {
  __builtin_amdgcn_global_load_lds(
    (const __attribute__((address_space(1))) void*)g,
    (__attribute__((address_space(3))) void*)l, 16, 0, 0);
}

// ---------------- fused prep: cast x -> bf16, transpose W_attn & W_proj -> bf16 ----------------
extern "C" __global__ __launch_bounds__(1024) void k_prep(
    const float* __restrict__ x, u16* __restrict__ xb,
    const float* __restrict__ Wa, u16* __restrict__ wat,
    const float* __restrict__ Wp, u16* __restrict__ wpt)
{
  __shared__ float t[32][33];
  int bid = blockIdx.x, tid = threadIdx.x;
  if (bid < 1024) {
    int i = bid * 1024 + tid;
    float4 v = ((const float4*)x)[i];
    union { u16 h[4]; uint2 u; } o;
    o.h[0] = f2bf(v.x); o.h[1] = f2bf(v.y); o.h[2] = f2bf(v.z); o.h[3] = f2bf(v.w);
    ((uint2*)xb)[i] = o.u;
    return;
  }
  const float* in; u16* out; int Ccols, bx, by;
  if (bid < 4096) { int tt = bid - 1024; in = Wa; out = wat; Ccols = 3072; bx = tt % 96; by = tt / 96; }
  else            { int tt = bid - 4096; in = Wp; out = wpt; Ccols = 1024; bx = tt & 31; by = tt >> 5; }
  int tx = tid & 31, ty = tid >> 5;
  int c0 = bx * 32, r0 = by * 32;
  t[ty][tx] = in[(size_t)(r0 + ty) * Ccols + c0 + tx];
  __syncthreads();
  out[(size_t)(c0 + ty) * 1024 + r0 + tx] = f2bf(t[tx][ty]);
}

// ---------------- QKV GEMM, 2-phase pipelined, 128x96 tiles (4 blocks/CU), fused V-transpose ----------------
// Same proven 2-phase handshake and 4-wave structure; tile narrowed 128x128 -> 128x96
// so grid = (32,32) = 1024 blocks = 4 blocks/CU (was 768 = 3/CU). R14 showed more
// waves WITHIN a block are null (barrier-locked); more independent blocks per CU are
// the real TLP (m103's 912 TF ran 4 blocks/CU). LDS 28 KB, per-wave 64x48 (acc[4][3]).
// V-boundary branch stays wave-uniform: col base is a multiple of 16 and 2048 % 16 == 0.
extern "C" __global__ __launch_bounds__(256) void k_gemm_qkv(
    const u16* __restrict__ A, const u16* __restrict__ Bt,
    const float* __restrict__ bias, u16* __restrict__ qkv, u16* __restrict__ vt)
{
  const int K = 1024, N = 3072;
  __shared__ u16 lds_a[2][128 * 32];
  __shared__ u16 lds_b[2][96 * 32];
  int tid = threadIdx.x;
  int w = tid >> 6, l = tid & 63;
  int lg = l >> 4, lr = l & 15;
  int nwg = gridDim.x * gridDim.y;               // 1024
  int lin = blockIdx.y * gridDim.x + blockIdx.x;
  int cpx = nwg >> 3;
  int swz = (lin & 7) * cpx + (lin >> 3);
  int m0 = (swz / gridDim.x) * 128, n0 = (swz % gridDim.x) * 96;
  int wm = w >> 1, wn = w & 1;
  f32x4 acc[4][3];
#pragma unroll
  for (int i = 0; i < 4; ++i)
#pragma unroll
    for (int j = 0; j < 3; ++j) acc[i][j] = (f32x4){0.f, 0.f, 0.f, 0.f};

  auto STAGE = [&](int k0, int buf) {
    // A: 8 chunks (1 KB = 16 rows x 64 B); wave w stages chunks {2w, 2w+1}
#pragma unroll
    for (int j = 0; j < 2; ++j) {
      int ci = w * 2 + j;
      gload_lds16(A + (size_t)(m0 + ci * 16 + (l >> 2)) * K + k0 + (l & 3) * 8,
                  (char*)lds_a[buf] + ci * 1024);
    }
    // B: 6 chunks; wave w stages chunk w, waves 0/1 also chunks 4/5
    gload_lds16(Bt + (size_t)(n0 + w * 16 + (l >> 2)) * K + k0 + (l & 3) * 8,
                (char*)lds_b[buf] + w * 1024);
    if (w < 2)
      gload_lds16(Bt + (size_t)(n0 + (w + 4) * 16 + (l >> 2)) * K + k0 + (l & 3) * 8,
                  (char*)lds_b[buf] + (w + 4) * 1024);
  };

  int nt = K >> 5;
  STAGE(0, 0);
  int cur = 0;
  for (int t = 0; t < nt; ++t) {
    asm volatile("s_waitcnt vmcnt(0)" ::: "memory");
    __syncthreads();
    if (t + 1 < nt) STAGE((t + 1) << 5, cur ^ 1);
    shortx8 af[4], bf[3];
#pragma unroll
    for (int i = 0; i < 4; ++i)
      af[i] = *(const shortx8*)((const char*)lds_a[cur] + (64 * wm + 16 * i + lr) * 64 + lg * 16);
#pragma unroll
    for (int i = 0; i < 3; ++i)
      bf[i] = *(const shortx8*)((const char*)lds_b[cur] + (48 * wn + 16 * i + lr) * 64 + lg * 16);
    __builtin_amdgcn_s_setprio(1);
#pragma unroll
    for (int mi = 0; mi < 4; ++mi)
#pragma unroll
      for (int ni = 0; ni < 3; ++ni)
        acc[mi][ni] = MFMA16(af[mi], bf[ni], acc[mi][ni]);
    __builtin_amdgcn_s_setprio(0);
    cur ^= 1;
  }
  // epilogue: Q,K -> qkv; V -> vt (transposed)
#pragma unroll
  for (int mi = 0; mi < 4; ++mi)
#pragma unroll
    for (int ni = 0; ni < 3; ++ni) {
      int col = n0 + 48 * wn + 16 * ni + lr;
      float bz = bias[col];
      int row0 = m0 + 64 * wm + 16 * mi + 4 * lg;
      if (col < 2048) {
#pragma unroll
        for (int r = 0; r < 4; ++r)
          qkv[(size_t)(row0 + r) * N + col] = f2bf(acc[mi][ni][r] + bz);
      } else {
        int dall = col - 2048;
        int h = dall >> 6, dd = dall & 63;
        int b_ = row0 >> 11, t_ = row0 & 2047;
        shortx4 o;
#pragma unroll
        for (int r = 0; r < 4; ++r) o[r] = (short)f2bf(acc[mi][ni][r] + bz);
        *(shortx4*)(vt + (size_t)((b_ * H_NUM + h) * DH + dd) * TSEQ + t_) = o;
      }
    }
}

// ---------------- y-projection GEMM, 2-phase pipelined, 64x128 tiles, f32 out ----------------
// (byte-identical to the R13/R14 green kernel)
extern "C" __global__ __launch_bounds__(256) void k_gemm_y(
    const u16* __restrict__ A, const u16* __restrict__ Bt,
    const float* __restrict__ bias, float* __restrict__ Cout)
{
  const int K = 1024, N = 1024;
  __shared__ u16 lds_a[2][64 * 32];
  __shared__ u16 lds_b[2][128 * 32];
  int tid = threadIdx.x;
  int w = tid >> 6, l = tid & 63;
  int lg = l >> 4, lr = l & 15;
  int nwg = gridDim.x * gridDim.y;
  int lin = blockIdx.y * gridDim.x + blockIdx.x;
  int cpx = nwg >> 3;
  int swz = (lin & 7) * cpx + (lin >> 3);
  int m0 = (swz / gridDim.x) * 64, n0 = (swz % gridDim.x) * 128;
  f32x4 acc[4][2];
#pragma unroll
  for (int i = 0; i < 4; ++i)
#pragma unroll
    for (int j = 0; j < 2; ++j) acc[i][j] = (f32x4){0.f, 0.f, 0.f, 0.f};

  auto STAGE = [&](int k0, int buf) {
    gload_lds16(A + (size_t)(m0 + w * 16 + (l >> 2)) * K + k0 + (l & 3) * 8,
                (char*)lds_a[buf] + w * 1024);
#pragma unroll
    for (int j = 0; j < 2; ++j) {
      int ci = w * 2 + j;
      gload_lds16(Bt + (size_t)(n0 + ci * 16 + (l >> 2)) * K + k0 + (l & 3) * 8,
                  (char*)lds_b[buf] + ci * 1024);
    }
  };

  int nt = K >> 5;
  STAGE(0, 0);
  int cur = 0;
  for (int t = 0; t < nt; ++t) {
    asm volatile("s_waitcnt vmcnt(0)" ::: "memory");
    __syncthreads();
    if (t + 1 < nt) STAGE((t + 1) << 5, cur ^ 1);
    shortx8 af[4], bf[2];
#pragma unroll
    for (int i = 0; i < 4; ++i)
      af[i] = *(const shortx8*)((const char*)lds_a[cur] + (16 * i + lr) * 64 + lg * 16);
#pragma unroll
    for (int i = 0; i < 2; ++i)
      bf[i] = *(const shortx8*)((const char*)lds_b[cur] + (32 * w + 16 * i + lr) * 64 + lg * 16);
    __builtin_amdgcn_s_setprio(1);
#pragma unroll
    for (int mi = 0; mi < 4; ++mi)
#pragma unroll
      for (int ni = 0; ni < 2; ++ni)
        acc[mi][ni] = MFMA16(af[mi], bf[ni], acc[mi][ni]);
    __builtin_amdgcn_s_setprio(0);
    cur ^= 1;
  }
#pragma unroll
  for (int mi = 0; mi < 4; ++mi)
#pragma unroll
    for (int ni = 0; ni < 2; ++ni) {
      int col = n0 + 32 * w + 16 * ni + lr;
      float bz = bias[col];
#pragma unroll
      for (int r = 0; r < 4; ++r) {
        int row = m0 + 16 * mi + 4 * lg + r;
        Cout[(size_t)row * N + col] = acc[mi][ni][r] + bz;
      }
    }
}

// ---------------- flash attention, causal, paired q-tiles, KVBLK=128 ----------------
// (byte-identical to the R7/R12/R13/R14 green kernel: grid 512, 17 tiles/block, 80 KB LDS)
extern "C" __global__ __launch_bounds__(256) void k_attn(
    const u16* __restrict__ qkv, const u16* __restrict__ vt, u16* __restrict__ yb)
{
  __shared__ u16 lds_k[2][128 * 64];   // [buf][kv][d], rows 128B, XOR-swizzled chunks
  __shared__ u16 lds_v[2][64 * 128];   // [buf][d][kv], rows 256B, XOR-swizzled chunks
  __shared__ u16 lds_p[4 * 2048];      // per-wave [16 q][128 kv]
  int d = blockIdx.x;                 // 0..511
  int xcd = d & 7, j = d >> 3;
  int hb = xcd + 8 * (j >> 4);
  int bx = j & 15;
  int h = hb & 15, b = hb >> 4;
  int tid = threadIdx.x, w = tid >> 6, l = tid & 63;
  int lg = l >> 4, lr = l & 15;
  const float QSCALE = 0.18033688011112042f;  // 0.125 * log2(e)
  const u16* vbase = vt + (size_t)(b * H_NUM + h) * DH * TSEQ;
  u16* pw = lds_p + w * 2048;

  auto STAGE = [&](int kv0, int buf) {
#pragma unroll
    for (int jj = 0; jj < 4; ++jj) {
      int ci = w * 4 + jj;
      int krow = ci * 8 + (l >> 3);
      int ka = ((l & 7) ^ (krow & 7)) * 8;
      gload_lds16(qkv + (size_t)(b * TSEQ + kv0 + krow) * 3072 + CDIM + h * DH + ka,
                  (char*)lds_k[buf] + ci * 1024);
      int vrow = ci * 4 + (l >> 4);
      int va = ((l & 15) ^ (vrow & 15)) * 8;
      gload_lds16(vbase + (size_t)vrow * TSEQ + kv0 + va,
                  (char*)lds_v[buf] + ci * 1024);
    }
  };

  for (int qi = 0; qi < 2; ++qi) {
    int qb = qi ? (31 - bx) : bx;
    int q0 = qb * 64;

    int qrow = q0 + 16 * w + lr;
    const u16* qp = qkv + (size_t)(b * TSEQ + qrow) * 3072 + h * DH;
    shortx8 qf[2];
#pragma unroll
    for (int s_ = 0; s_ < 2; ++s_) {
      shortx8 v = *(const shortx8*)(qp + s_ * 32 + lg * 8);
#pragma unroll
      for (int i = 0; i < 8; ++i) v[i] = (short)f2bf(bf2f((u16)v[i]) * QSCALE);
      qf[s_] = v;
    }

    f32x4 yacc[4];
#pragma unroll
    for (int i = 0; i < 4; ++i) yacc[i] = (f32x4){0.f, 0.f, 0.f, 0.f};
    float m_run[4] = {-3.0e38f, -3.0e38f, -3.0e38f, -3.0e38f};
    float l_part[4] = {0.f, 0.f, 0.f, 0.f};

    int nt = (qb >> 1) + 1;     // tiles of 128 kv
    __syncthreads();            // previous readers of buf0 done
    STAGE(0, 0);
    int cur = 0;
    for (int t = 0; t < nt; ++t) {
      int kv0 = t * 128;
      asm volatile("s_waitcnt vmcnt(0)" ::: "memory");
      __syncthreads();          // buf[cur] complete & visible to all waves
      if (t + 1 < nt) STAGE(kv0 + 128, cur ^ 1);

      // ---- QK^T over 128 kv ----
      f32x4 s[8];
#pragma unroll
      for (int idx = 0; idx < 8; ++idx) s[idx] = (f32x4){0.f, 0.f, 0.f, 0.f};
      int kswz = (lr & 7) << 4;
      __builtin_amdgcn_s_setprio(1);
#pragma unroll
      for (int idx = 0; idx < 8; ++idx) {
        const char* kb_ = (const char*)lds_k[cur] + (idx * 16 + lr) * 128;
#pragma unroll
        for (int d0 = 0; d0 < 2; ++d0) {
          shortx8 kf = *(const shortx8*)(kb_ + ((d0 * 64 + lg * 16) ^ kswz));
          s[idx] = MFMA16(qf[d0], kf, s[idx]);
        }
      }
      __builtin_amdgcn_s_setprio(0);
      if (t == nt - 1) {        // only tile where kv can exceed q
        int base = q0 - kv0 + 16 * w + 4 * lg;
#pragma unroll
        for (int idx = 0; idx < 8; ++idx)
#pragma unroll
          for (int r = 0; r < 4; ++r)
            if (idx * 16 + lr > base + r) s[idx][r] = -3.0e38f;
      }

      // ---- online softmax (one pass per 128-kv tile) ----
#pragma unroll
      for (int r = 0; r < 4; ++r) {
        float a0 = s[0][r], a1 = s[1][r], a2 = s[2][r], a3 = s[3][r];
        float a4 = s[4][r], a5 = s[5][r], a6 = s[6][r], a7 = s[7][r];
        float pmax = fmaxf(fmaxf(fmaxf(a0, a1), fmaxf(a2, a3)),
                           fmaxf(fmaxf(a4, a5), fmaxf(a6, a7)));
        float mr = m_run[r];
        u64 bal = __ballot(pmax > mr + 8.0f);
        if ((bal >> (lg * 16)) & 0xFFFFull) {
          float gm = pmax;
          gm = fmaxf(gm, __shfl_xor(gm, 1));
          gm = fmaxf(gm, __shfl_xor(gm, 2));
          gm = fmaxf(gm, __shfl_xor(gm, 4));
          gm = fmaxf(gm, __shfl_xor(gm, 8));
          float mn = fmaxf(mr, gm);
          float al = __builtin_amdgcn_exp2f(mr - mn);
          l_part[r] *= al;
#pragma unroll
          for (int dt = 0; dt < 4; ++dt) yacc[dt][r] *= al;
          m_run[r] = mn; mr = mn;
        }
        float p0 = __builtin_amdgcn_exp2f(a0 - mr);
        float p1 = __builtin_amdgcn_exp2f(a1 - mr);
        float p2 = __builtin_amdgcn_exp2f(a2 - mr);
        float p3 = __builtin_amdgcn_exp2f(a3 - mr);
        float p4 = __builtin_amdgcn_exp2f(a4 - mr);
        float p5 = __builtin_amdgcn_exp2f(a5 - mr);
        float p6 = __builtin_amdgcn_exp2f(a6 - mr);
        float p7 = __builtin_amdgcn_exp2f(a7 - mr);
        l_part[r] += ((p0 + p1) + (p2 + p3)) + ((p4 + p5) + (p6 + p7));
        u32 pk01, pk23, pk45, pk67;
        asm("v_cvt_pk_bf16_f32 %0, %1, %2" : "=v"(pk01) : "v"(p0), "v"(p1));
        asm("v_cvt_pk_bf16_f32 %0, %1, %2" : "=v"(pk23) : "v"(p2), "v"(p3));
        asm("v_cvt_pk_bf16_f32 %0, %1, %2" : "=v"(pk45) : "v"(p4), "v"(p5));
        asm("v_cvt_pk_bf16_f32 %0, %1, %2" : "=v"(pk67) : "v"(p6), "v"(p7));
        int q = 4 * lg + r;
        int rb = q * 128, swq = (q & 7) << 3;
        pw[rb + ((lr)       ^ swq)] = (u16)pk01;
        pw[rb + ((16 + lr)  ^ swq)] = (u16)(pk01 >> 16);
        pw[rb + ((32 + lr)  ^ swq)] = (u16)pk23;
        pw[rb + ((48 + lr)  ^ swq)] = (u16)(pk23 >> 16);
        pw[rb + ((64 + lr)  ^ swq)] = (u16)pk45;
        pw[rb + ((80 + lr)  ^ swq)] = (u16)(pk45 >> 16);
        pw[rb + ((96 + lr)  ^ swq)] = (u16)pk67;
        pw[rb + ((112 + lr) ^ swq)] = (u16)(pk67 >> 16);
      }
      asm volatile("s_waitcnt lgkmcnt(0)" ::: "memory");
      __builtin_amdgcn_sched_barrier(0);

      // ---- PV over 128 kv ----
      int pswz = (lr & 7) << 4;
      __builtin_amdgcn_s_setprio(1);
#pragma unroll
      for (int c = 0; c < 4; ++c) {
        shortx8 pa = *(const shortx8*)((const char*)pw + lr * 256 + ((c * 64 + lg * 16) ^ pswz));
#pragma unroll
        for (int dt = 0; dt < 4; ++dt) {
          int vr = dt * 16 + lr;
          shortx8 vf = *(const shortx8*)((const char*)lds_v[cur] + vr * 256 +
                         (((c * 4 + lg) ^ (vr & 15)) << 4));
          yacc[dt] = MFMA16(pa, vf, yacc[dt]);
        }
      }
      __builtin_amdgcn_s_setprio(0);
      cur ^= 1;
    }

    // epilogue: reduce deferred l, normalize, store
#pragma unroll
    for (int r = 0; r < 4; ++r) {
      float lsum = l_part[r];
      lsum += __shfl_xor(lsum, 1);
      lsum += __shfl_xor(lsum, 2);
      lsum += __shfl_xor(lsum, 4);
      lsum += __shfl_xor(lsum, 8);
      float inv = 1.0f / lsum;
      int row = q0 + 16 * w + 4 * lg + r;
      u16* yp = yb + (size_t)(b * TSEQ + row) * CDIM + h * DH;
#pragma unroll
      for (int dt = 0; dt < 4; ++dt)
        yp[dt * 16 + lr] = f2bf(yacc[dt][r] * inv);
    }
  }
}

extern "C" void kernel_launch(void* const* d_in, const int* in_sizes, int n_in,
                              void* d_out, int out_size, void* d_ws, size_t ws_size,
                              hipStream_t stream) {
  const float* x      = (const float*)d_in[0];
  const float* W_attn = (const float*)d_in[2];
  const float* b_attn = (const float*)d_in[3];
  const float* W_proj = (const float*)d_in[4];
  const float* b_proj = (const float*)d_in[5];

  char* ws = (char*)d_ws;
  u16* xb  = (u16*)ws;                         // 8 MB  [4096][1024]
  u16* wat = (u16*)(ws + (8ull  << 20));       // 6 MB  [3072][1024]
  u16* wpt = (u16*)(ws + (14ull << 20));       // 2 MB  [1024][1024]
  u16* qkv = (u16*)(ws + (16ull << 20));       // 24 MB [4096][3072] (V region unused)
  u16* vt  = (u16*)(ws + (40ull << 20));       // 8 MB  [32*64][2048]
  u16* yb  = (u16*)(ws + (48ull << 20));       // 8 MB  [4096][1024]

  k_prep<<<dim3(5120), dim3(1024), 0, stream>>>(x, xb, W_attn, wat, W_proj, wpt);
  k_gemm_qkv<<<dim3(32, 32), dim3(256), 0, stream>>>(xb, wat, b_attn, qkv, vt);
  k_attn<<<dim3(512), dim3(256), 0, stream>>>(qkv, vt, yb);
  k_gemm_y<<<dim3(8, 64), dim3(256), 0, stream>>>(yb, wpt, b_proj, (float*)d_out);
}

// Round 16
// 118.135 us; speedup vs baseline: 1.0169x; 1.0169x over previous
//
#include <hip/hip_runtime.h>
#include <hip/hip_bf16.h>
#include <stdint.h>

#define H_NUM 16
#define DH 64
#define TSEQ 2048
#define CDIM 1024

typedef short shortx8 __attribute__((ext_vector_type(8)));
typedef short shortx4 __attribute__((ext_vector_type(4)));
typedef float f32x4 __attribute__((ext_vector_type(4)));
typedef unsigned short u16;
typedef unsigned int u32;
typedef unsigned long long u64;

#define MFMA16(a,b,c) __builtin_amdgcn_mfma_f32_16x16x32_bf16(a,b,c,0,0,0)

static __device__ __forceinline__ u16 f2bf(float f) {
  union { float f; u32 u; } v; v.f = f;
  u32 r = v.u + 0x7fffu + ((v.u >> 16) & 1u);
  return (u16)(r >> 16);
}
static __device__ __forceinline__ float bf2f(u16 b) {
  union { u32 u; float f; } v; v.u = ((u32)b) << 16;
  return v.f;
}

static __device__ __forceinline__ void gload_lds16(const void* g, void* l) {
  __builtin_amdgcn_global_load_lds(
    (const __attribute__((address_space(1))) void*)g,
    (__attribute__((address_space(3))) void*)l, 16, 0, 0);
}

// ---------------- fused prep: cast x -> bf16, transpose W_attn & W_proj -> bf16 ----------------
extern "C" __global__ __launch_bounds__(1024) void k_prep(
    const float* __restrict__ x, u16* __restrict__ xb,
    const float* __restrict__ Wa, u16* __restrict__ wat,
    const float* __restrict__ Wp, u16* __restrict__ wpt)
{
  __shared__ float t[32][33];
  int bid = blockIdx.x, tid = threadIdx.x;
  if (bid < 1024) {
    int i = bid * 1024 + tid;
    float4 v = ((const float4*)x)[i];
    union { u16 h[4]; uint2 u; } o;
    o.h[0] = f2bf(v.x); o.h[1] = f2bf(v.y); o.h[2] = f2bf(v.z); o.h[3] = f2bf(v.w);
    ((uint2*)xb)[i] = o.u;
    return;
  }
  const float* in; u16* out; int Ccols, bx, by;
  if (bid < 4096) { int tt = bid - 1024; in = Wa; out = wat; Ccols = 3072; bx = tt % 96; by = tt / 96; }
  else            { int tt = bid - 4096; in = Wp; out = wpt; Ccols = 1024; bx = tt & 31; by = tt >> 5; }
  int tx = tid & 31, ty = tid >> 5;
  int c0 = bx * 32, r0 = by * 32;
  t[ty][tx] = in[(size_t)(r0 + ty) * Ccols + c0 + tx];
  __syncthreads();
  out[(size_t)(c0 + ty) * 1024 + r0 + tx] = f2bf(t[tx][ty]);
}

// ---------------- QKV GEMM, 2-phase pipelined, 128x128 block tile, 8 waves, fused V-transpose ----------------
// (byte-identical to the R14 session-best kernel)
extern "C" __global__ __launch_bounds__(512) void k_gemm_qkv(
    const u16* __restrict__ A, const u16* __restrict__ Bt,
    const float* __restrict__ bias, u16* __restrict__ qkv, u16* __restrict__ vt)
{
  const int K = 1024, N = 3072;
  __shared__ u16 lds_a[2][128 * 32];
  __shared__ u16 lds_b[2][128 * 32];
  int tid = threadIdx.x;
  int w = tid >> 6, l = tid & 63;
  int lg = l >> 4, lr = l & 15;
  int nwg = gridDim.x * gridDim.y;
  int lin = blockIdx.y * gridDim.x + blockIdx.x;
  int cpx = nwg >> 3;
  int swz = (lin & 7) * cpx + (lin >> 3);
  int m0 = (swz / gridDim.x) * 128, n0 = (swz % gridDim.x) * 128;
  int wm = w >> 2, wn = w & 3;
  f32x4 acc[4][2];
#pragma unroll
  for (int i = 0; i < 4; ++i)
#pragma unroll
    for (int j = 0; j < 2; ++j) acc[i][j] = (f32x4){0.f, 0.f, 0.f, 0.f};

  auto STAGE = [&](int k0, int buf) {
    gload_lds16(A  + (size_t)(m0 + w * 16 + (l >> 2)) * K + k0 + (l & 3) * 8,
                (char*)lds_a[buf] + w * 1024);
    gload_lds16(Bt + (size_t)(n0 + w * 16 + (l >> 2)) * K + k0 + (l & 3) * 8,
                (char*)lds_b[buf] + w * 1024);
  };

  int nt = K >> 5;
  STAGE(0, 0);
  int cur = 0;
  for (int t = 0; t < nt; ++t) {
    asm volatile("s_waitcnt vmcnt(0)" ::: "memory");
    __syncthreads();
    if (t + 1 < nt) STAGE((t + 1) << 5, cur ^ 1);
    shortx8 af[4], bf[2];
#pragma unroll
    for (int i = 0; i < 4; ++i)
      af[i] = *(const shortx8*)((const char*)lds_a[cur] + (64 * wm + 16 * i + lr) * 64 + lg * 16);
#pragma unroll
    for (int i = 0; i < 2; ++i)
      bf[i] = *(const shortx8*)((const char*)lds_b[cur] + (32 * wn + 16 * i + lr) * 64 + lg * 16);
    __builtin_amdgcn_s_setprio(1);
#pragma unroll
    for (int mi = 0; mi < 4; ++mi)
#pragma unroll
      for (int ni = 0; ni < 2; ++ni)
        acc[mi][ni] = MFMA16(af[mi], bf[ni], acc[mi][ni]);
    __builtin_amdgcn_s_setprio(0);
    cur ^= 1;
  }
  // epilogue: Q,K -> qkv; V -> vt (transposed)
#pragma unroll
  for (int mi = 0; mi < 4; ++mi)
#pragma unroll
    for (int ni = 0; ni < 2; ++ni) {
      int col = n0 + 32 * wn + 16 * ni + lr;
      float bz = bias[col];
      int row0 = m0 + 64 * wm + 16 * mi + 4 * lg;
      if (col < 2048) {
#pragma unroll
        for (int r = 0; r < 4; ++r)
          qkv[(size_t)(row0 + r) * N + col] = f2bf(acc[mi][ni][r] + bz);
      } else {
        int dall = col - 2048;
        int h = dall >> 6, dd = dall & 63;
        int b_ = row0 >> 11, t_ = row0 & 2047;
        shortx4 o;
#pragma unroll
        for (int r = 0; r < 4; ++r) o[r] = (short)f2bf(acc[mi][ni][r] + bz);
        *(shortx4*)(vt + (size_t)((b_ * H_NUM + h) * DH + dd) * TSEQ + t_) = o;
      }
    }
}

// ---------------- y-projection GEMM, 2-phase pipelined, 64x128 tiles, f32 out ----------------
// (byte-identical to the R13/R14 green kernel)
extern "C" __global__ __launch_bounds__(256) void k_gemm_y(
    const u16* __restrict__ A, const u16* __restrict__ Bt,
    const float* __restrict__ bias, float* __restrict__ Cout)
{
  const int K = 1024, N = 1024;
  __shared__ u16 lds_a[2][64 * 32];
  __shared__ u16 lds_b[2][128 * 32];
  int tid = threadIdx.x;
  int w = tid >> 6, l = tid & 63;
  int lg = l >> 4, lr = l & 15;
  int nwg = gridDim.x * gridDim.y;
  int lin = blockIdx.y * gridDim.x + blockIdx.x;
  int cpx = nwg >> 3;
  int swz = (lin & 7) * cpx + (lin >> 3);
  int m0 = (swz / gridDim.x) * 64, n0 = (swz % gridDim.x) * 128;
  f32x4 acc[4][2];
#pragma unroll
  for (int i = 0; i < 4; ++i)
#pragma unroll
    for (int j = 0; j < 2; ++j) acc[i][j] = (f32x4){0.f, 0.f, 0.f, 0.f};

  auto STAGE = [&](int k0, int buf) {
    gload_lds16(A + (size_t)(m0 + w * 16 + (l >> 2)) * K + k0 + (l & 3) * 8,
                (char*)lds_a[buf] + w * 1024);
#pragma unroll
    for (int j = 0; j < 2; ++j) {
      int ci = w * 2 + j;
      gload_lds16(Bt + (size_t)(n0 + ci * 16 + (l >> 2)) * K + k0 + (l & 3) * 8,
                  (char*)lds_b[buf] + ci * 1024);
    }
  };

  int nt = K >> 5;
  STAGE(0, 0);
  int cur = 0;
  for (int t = 0; t < nt; ++t) {
    asm volatile("s_waitcnt vmcnt(0)" ::: "memory");
    __syncthreads();
    if (t + 1 < nt) STAGE((t + 1) << 5, cur ^ 1);
    shortx8 af[4], bf[2];
#pragma unroll
    for (int i = 0; i < 4; ++i)
      af[i] = *(const shortx8*)((const char*)lds_a[cur] + (16 * i + lr) * 64 + lg * 16);
#pragma unroll
    for (int i = 0; i < 2; ++i)
      bf[i] = *(const shortx8*)((const char*)lds_b[cur] + (32 * w + 16 * i + lr) * 64 + lg * 16);
    __builtin_amdgcn_s_setprio(1);
#pragma unroll
    for (int mi = 0; mi < 4; ++mi)
#pragma unroll
      for (int ni = 0; ni < 2; ++ni)
        acc[mi][ni] = MFMA16(af[mi], bf[ni], acc[mi][ni]);
    __builtin_amdgcn_s_setprio(0);
    cur ^= 1;
  }
#pragma unroll
  for (int mi = 0; mi < 4; ++mi)
#pragma unroll
    for (int ni = 0; ni < 2; ++ni) {
      int col = n0 + 32 * w + 16 * ni + lr;
      float bz = bias[col];
#pragma unroll
      for (int r = 0; r < 4; ++r) {
        int row = m0 + 16 * mi + 4 * lg + r;
        Cout[(size_t)row * N + col] = acc[mi][ni][r] + bz;
      }
    }
}

// ---------------- flash attention, causal, paired q-tiles, KVBLK=128 ----------------
// (byte-identical to the R7-lineage green kernel: grid 512, 17 tiles/block, 80 KB LDS)
extern "C" __global__ __launch_bounds__(256) void k_attn(
    const u16* __restrict__ qkv, const u16* __restrict__ vt, u16* __restrict__ yb)
{
  __shared__ u16 lds_k[2][128 * 64];   // [buf][kv][d], rows 128B, XOR-swizzled chunks
  __shared__ u16 lds_v[2][64 * 128];   // [buf][d][kv], rows 256B, XOR-swizzled chunks
  __shared__ u16 lds_p[4 * 2048];      // per-wave [16 q][128 kv]
  int d = blockIdx.x;                 // 0..511
  int xcd = d & 7, j = d >> 3;
  int hb = xcd + 8 * (j >> 4);
  int bx = j & 15;
  int h = hb & 15, b = hb >> 4;
  int tid = threadIdx.x, w = tid >> 6, l = tid & 63;
  int lg = l >> 4, lr = l & 15;
  const float QSCALE = 0.18033688011112042f;  // 0.125 * log2(e)
  const u16* vbase = vt + (size_t)(b * H_NUM + h) * DH * TSEQ;
  u16* pw = lds_p + w * 2048;

  auto STAGE = [&](int kv0, int buf) {
#pragma unroll
    for (int jj = 0; jj < 4; ++jj) {
      int ci = w * 4 + jj;
      int krow = ci * 8 + (l >> 3);
      int ka = ((l & 7) ^ (krow & 7)) * 8;
      gload_lds16(qkv + (size_t)(b * TSEQ + kv0 + krow) * 3072 + CDIM + h * DH + ka,
                  (char*)lds_k[buf] + ci * 1024);
      int vrow = ci * 4 + (l >> 4);
      int va = ((l & 15) ^ (vrow & 15)) * 8;
      gload_lds16(vbase + (size_t)vrow * TSEQ + kv0 + va,
                  (char*)lds_v[buf] + ci * 1024);
    }
  };

  for (int qi = 0; qi < 2; ++qi) {
    int qb = qi ? (31 - bx) : bx;
    int q0 = qb * 64;

    int qrow = q0 + 16 * w + lr;
    const u16* qp = qkv + (size_t)(b * TSEQ + qrow) * 3072 + h * DH;
    shortx8 qf[2];
#pragma unroll
    for (int s_ = 0; s_ < 2; ++s_) {
      shortx8 v = *(const shortx8*)(qp + s_ * 32 + lg * 8);
#pragma unroll
      for (int i = 0; i < 8; ++i) v[i] = (short)f2bf(bf2f((u16)v[i]) * QSCALE);
      qf[s_] = v;
    }

    f32x4 yacc[4];
#pragma unroll
    for (int i = 0; i < 4; ++i) yacc[i] = (f32x4){0.f, 0.f, 0.f, 0.f};
    float m_run[4] = {-3.0e38f, -3.0e38f, -3.0e38f, -3.0e38f};
    float l_part[4] = {0.f, 0.f, 0.f, 0.f};

    int nt = (qb >> 1) + 1;     // tiles of 128 kv
    __syncthreads();            // previous readers of buf0 done
    STAGE(0, 0);
    int cur = 0;
    for (int t = 0; t < nt; ++t) {
      int kv0 = t * 128;
      asm volatile("s_waitcnt vmcnt(0)" ::: "memory");
      __syncthreads();          // buf[cur] complete & visible to all waves
      if (t + 1 < nt) STAGE(kv0 + 128, cur ^ 1);

      // ---- QK^T over 128 kv ----
      f32x4 s[8];
#pragma unroll
      for (int idx = 0; idx < 8; ++idx) s[idx] = (f32x4){0.f, 0.f, 0.f, 0.f};
      int kswz = (lr & 7) << 4;
      __builtin_amdgcn_s_setprio(1);
#pragma unroll
      for (int idx = 0; idx < 8; ++idx) {
        const char* kb_ = (const char*)lds_k[cur] + (idx * 16 + lr) * 128;
#pragma unroll
        for (int d0 = 0; d0 < 2; ++d0) {
          shortx8 kf = *(const shortx8*)(kb_ + ((d0 * 64 + lg * 16) ^ kswz));
          s[idx] = MFMA16(qf[d0], kf, s[idx]);
        }
      }
      __builtin_amdgcn_s_setprio(0);
      if (t == nt - 1) {        // only tile where kv can exceed q
        int base = q0 - kv0 + 16 * w + 4 * lg;
#pragma unroll
        for (int idx = 0; idx < 8; ++idx)
#pragma unroll
          for (int r = 0; r < 4; ++r)
            if (idx * 16 + lr > base + r) s[idx][r] = -3.0e38f;
      }

      // ---- online softmax (one pass per 128-kv tile) ----
#pragma unroll
      for (int r = 0; r < 4; ++r) {
        float a0 = s[0][r], a1 = s[1][r], a2 = s[2][r], a3 = s[3][r];
        float a4 = s[4][r], a5 = s[5][r], a6 = s[6][r], a7 = s[7][r];
        float pmax = fmaxf(fmaxf(fmaxf(a0, a1), fmaxf(a2, a3)),
                           fmaxf(fmaxf(a4, a5), fmaxf(a6, a7)));
        float mr = m_run[r];
        u64 bal = __ballot(pmax > mr + 8.0f);
        if ((bal >> (lg * 16)) & 0xFFFFull) {
          float gm = pmax;
          gm = fmaxf(gm, __shfl_xor(gm, 1));
          gm = fmaxf(gm, __shfl_xor(gm, 2));
          gm = fmaxf(gm, __shfl_xor(gm, 4));
          gm = fmaxf(gm, __shfl_xor(gm, 8));
          float mn = fmaxf(mr, gm);
          float al = __builtin_amdgcn_exp2f(mr - mn);
          l_part[r] *= al;
#pragma unroll
          for (int dt = 0; dt < 4; ++dt) yacc[dt][r] *= al;
          m_run[r] = mn; mr = mn;
        }
        float p0 = __builtin_amdgcn_exp2f(a0 - mr);
        float p1 = __builtin_amdgcn_exp2f(a1 - mr);
        float p2 = __builtin_amdgcn_exp2f(a2 - mr);
        float p3 = __builtin_amdgcn_exp2f(a3 - mr);
        float p4 = __builtin_amdgcn_exp2f(a4 - mr);
        float p5 = __builtin_amdgcn_exp2f(a5 - mr);
        float p6 = __builtin_amdgcn_exp2f(a6 - mr);
        float p7 = __builtin_amdgcn_exp2f(a7 - mr);
        l_part[r] += ((p0 + p1) + (p2 + p3)) + ((p4 + p5) + (p6 + p7));
        u32 pk01, pk23, pk45, pk67;
        asm("v_cvt_pk_bf16_f32 %0, %1, %2" : "=v"(pk01) : "v"(p0), "v"(p1));
        asm("v_cvt_pk_bf16_f32 %0, %1, %2" : "=v"(pk23) : "v"(p2), "v"(p3));
        asm("v_cvt_pk_bf16_f32 %0, %1, %2" : "=v"(pk45) : "v"(p4), "v"(p5));
        asm("v_cvt_pk_bf16_f32 %0, %1, %2" : "=v"(pk67) : "v"(p6), "v"(p7));
        int q = 4 * lg + r;
        int rb = q * 128, swq = (q & 7) << 3;
        pw[rb + ((lr)       ^ swq)] = (u16)pk01;
        pw[rb + ((16 + lr)  ^ swq)] = (u16)(pk01 >> 16);
        pw[rb + ((32 + lr)  ^ swq)] = (u16)pk23;
        pw[rb + ((48 + lr)  ^ swq)] = (u16)(pk23 >> 16);
        pw[rb + ((64 + lr)  ^ swq)] = (u16)pk45;
        pw[rb + ((80 + lr)  ^ swq)] = (u16)(pk45 >> 16);
        pw[rb + ((96 + lr)  ^ swq)] = (u16)pk67;
        pw[rb + ((112 + lr) ^ swq)] = (u16)(pk67 >> 16);
      }
      asm volatile("s_waitcnt lgkmcnt(0)" ::: "memory");
      __builtin_amdgcn_sched_barrier(0);

      // ---- PV over 128 kv ----
      int pswz = (lr & 7) << 4;
      __builtin_amdgcn_s_setprio(1);
#pragma unroll
      for (int c = 0; c < 4; ++c) {
        shortx8 pa = *(const shortx8*)((const char*)pw + lr * 256 + ((c * 64 + lg * 16) ^ pswz));
#pragma unroll
        for (int dt = 0; dt < 4; ++dt) {
          int vr = dt * 16 + lr;
          shortx8 vf = *(const shortx8*)((const char*)lds_v[cur] + vr * 256 +
                         (((c * 4 + lg) ^ (vr & 15)) << 4));
          yacc[dt] = MFMA16(pa, vf, yacc[dt]);
        }
      }
      __builtin_amdgcn_s_setprio(0);
      cur ^= 1;
    }

    // epilogue: reduce deferred l, normalize, store
#pragma unroll
    for (int r = 0; r < 4; ++r) {
      float lsum = l_part[r];
      lsum += __shfl_xor(lsum, 1);
      lsum += __shfl_xor(lsum, 2);
      lsum += __shfl_xor(lsum, 4);
      lsum += __shfl_xor(lsum, 8);
      float inv = 1.0f / lsum;
      int row = q0 + 16 * w + 4 * lg + r;
      u16* yp = yb + (size_t)(b * TSEQ + row) * CDIM + h * DH;
#pragma unroll
      for (int dt = 0; dt < 4; ++dt)
        yp[dt * 16 + lr] = f2bf(yacc[dt][r] * inv);
    }
  }
}

extern "C" void kernel_launch(void* const* d_in, const int* in_sizes, int n_in,
                              void* d_out, int out_size, void* d_ws, size_t ws_size,
                              hipStream_t stream) {
  const float* x      = (const float*)d_in[0];
  const float* W_attn = (const float*)d_in[2];
  const float* b_attn = (const float*)d_in[3];
  const float* W_proj = (const float*)d_in[4];
  const float* b_proj = (const float*)d_in[5];

  char* ws = (char*)d_ws;
  u16* xb  = (u16*)ws;                         // 8 MB  [4096][1024]
  u16* wat = (u16*)(ws + (8ull  << 20));       // 6 MB  [3072][1024]
  u16* wpt = (u16*)(ws + (14ull << 20));       // 2 MB  [1024][1024]
  u16* qkv = (u16*)(ws + (16ull << 20));       // 24 MB [4096][3072] (V region unused)
  u16* vt  = (u16*)(ws + (40ull << 20));       // 8 MB  [32*64][2048]
  u16* yb  = (u16*)(ws + (48ull << 20));       // 8 MB  [4096][1024]

  k_prep<<<dim3(5120), dim3(1024), 0, stream>>>(x, xb, W_attn, wat, W_proj, wpt);
  k_gemm_qkv<<<dim3(24, 32), dim3(512), 0, stream>>>(xb, wat, b_attn, qkv, vt);
  k_attn<<<dim3(512), dim3(256), 0, stream>>>(qkv, vt, yb);
  k_gemm_y<<<dim3(8, 64), dim3(256), 0, stream>>>(yb, wpt, b_proj, (float*)d_out);
}